// Round 7
// baseline (1552.468 us; speedup 1.0000x reference)
//
#include <hip/hip_runtime.h>

typedef unsigned int uint_t;

#define BB 64
#define TT 1024

__device__ __forceinline__ float sigm(float x) { return 1.f / (1.f + __expf(-x)); }
__device__ __forceinline__ float tanh_f(float x) { float e = __expf(2.f * x); return 1.f - 2.f / (e + 1.f); }
__device__ __forceinline__ int finitef(float x) { return (x == x) && (fabsf(x) < 1e30f); }

// Bounded wait on an LDS flag (monotone step counter) with s_sleep backoff.
// Naive spinning hammers the per-CU DS pipe (one ds_read per ~8cy) and steals
// issue slots from the working waves (R6: ~550 cy/step of unexplained period).
// s_sleep(1) parks the wave ~64cy between polls: poll traffic cut ~15x, discovery
// latency <= ~64cy per 4-step group. Cap => sync bug gives wrong answer, not hang.
__device__ __forceinline__ void spinwait(volatile int* f, int v) {
  if (*f >= v) { asm volatile("" ::: "memory"); return; }
  int it = 0;
  while (*f < v && it < (1 << 15)) { __builtin_amdgcn_s_sleep(1); ++it; }
  asm volatile("" ::: "memory");
}

// x feature j of token (b,t): [e_i(0..9) | e_j(10..19) | rbf(20..29)]
__device__ __forceinline__ float feat(int b, int t, int j,
                                      const int* atom_idx, const float* bond_dist,
                                      const float* emb) {
  int ii = atom_idx[(b * TT + t) * 2 + 0];
  if (j < 10) {
    return ii ? emb[ii * 10 + j] : 0.f;
  } else if (j < 20) {
    int jj = atom_idx[(b * TT + t) * 2 + 1];
    return jj ? emb[jj * 10 + (j - 10)] : 0.f;
  } else {
    float d = bond_dist[b * TT + t];
    float c = (float)(j - 19);
    float df = c - d;
    return ii ? __expf(-df * df) : 0.f;
  }
}

// ---------------- xw0 = x @ w_ih0.T + b_ih0  (time-parallel, K=30, G=192) ----------------
extern "C" __global__ void __launch_bounds__(256)
k_xw0(const int* atom_idx, const float* bond_dist, const float* emb,
      const float* w_ih0, const float* b_ih0, float* xw0) {
  int b  = blockIdx.x >> 4;
  int t0 = (blockIdx.x & 15) << 6;
  int tid = threadIdx.x;
  __shared__ float xt[64 * 31];
  for (int i = tid; i < 64 * 30; i += 256) {
    int r = i / 30, j = i % 30;
    xt[r * 31 + j] = feat(b, t0 + r, j, atom_idx, bond_dist, emb);
  }
  __syncthreads();
  for (int L = tid; L < 64 * 192; L += 256) {
    int g = L >> 6, r = L & 63;
    const float* wr = w_ih0 + g * 30;
    const float* ar = &xt[r * 31];
    float acc = b_ih0[g];
    #pragma unroll
    for (int c = 0; c < 30; ++c) acc += wr[c] * ar[c];
    xw0[((size_t)b * TT + t0 + r) * 192 + g] = acc;
  }
}

// ---------------- generic (64 rows) x (G x 64) GEMM ----------------
__device__ __forceinline__ void gemm64(const float* __restrict__ act_g,
                                       const float* __restrict__ w,
                                       const float* __restrict__ bias,
                                       float* al,
                                       int G, int tid,
                                       float* out, int out_rstride, size_t out_base) {
  for (int i = tid; i < 64 * 64; i += 256) {
    int r = i >> 6, c = i & 63;
    al[r * 65 + c] = act_g[r * 64 + c];
  }
  __syncthreads();
  for (int L = tid; L < 64 * G; L += 256) {
    int g = L >> 6, r = L & 63;
    const float* wr = w + (size_t)g * 64;
    const float* ar = &al[r * 65];
    float acc = bias[g];
    #pragma unroll
    for (int c = 0; c < 64; ++c) acc += wr[c] * ar[c];
    out[out_base + (size_t)r * out_rstride + g] = acc;
  }
}

// ---------------- fused GRU0 -> xw1 -> GRU1 : 3-stage wave pipeline, one block/batch ----------------
// wave0: layer-0 recurrence, h0(s) -> LDS ring.   wave1: xw1(t)=W_ih1.h0(t)+b -> LDS ring.
// wave2: layer-1 recurrence -> g1 global.
// RING DEPTH 16 (4 groups of slack); slot for group g reused only after the consumer
// signals group g-4 (wait threshold 4g-13). Sync: monotone LDS step counters,
// s_sleep-backoff waits (see spinwait), group-of-4 granularity.
extern "C" __global__ void __launch_bounds__(192, 1)
k_grufused(const float* xw0, const float* w_hh0, const float* b_hh0,
           const float* w_ih1, const float* b_ih1,
           const float* w_hh1, const float* b_hh1, float* g1out) {
  int b    = blockIdx.x;
  int lane = threadIdx.x & 63;
  int wid  = threadIdx.x >> 6;
  __shared__ __align__(16) float h0ring[16][64];
  __shared__ __align__(16) float xwring[16][192];
  __shared__ __align__(16) float h1pp[2][64];
  __shared__ int flags[3];        // w0_done, w1_done, w2_done

  if (threadIdx.x < 3) flags[threadIdx.x] = -1;
  if (wid == 0) h0ring[15][lane] = 0.f;  // h0(-1) = 0
  if (wid == 2) h1pp[0][lane] = 0.f;     // h1(-1) = 0
  __syncthreads();

  volatile int* w0d = &flags[0];
  volatile int* w1d = &flags[1];
  volatile int* w2d = &flags[2];

  if (wid == 0) {
    // ---- layer-0 recurrence ----
    float wr[64], wz[64], wn[64];
    {
      const float4* wrp = (const float4*)(w_hh0 + (size_t)lane * 64);
      const float4* wzp = (const float4*)(w_hh0 + (size_t)(64 + lane) * 64);
      const float4* wnp = (const float4*)(w_hh0 + (size_t)(128 + lane) * 64);
      #pragma unroll
      for (int i = 0; i < 16; ++i) {
        float4 a = wrp[i]; float4 c = wzp[i]; float4 d = wnp[i];
        wr[4*i] = a.x; wr[4*i+1] = a.y; wr[4*i+2] = a.z; wr[4*i+3] = a.w;
        wz[4*i] = c.x; wz[4*i+1] = c.y; wz[4*i+2] = c.z; wz[4*i+3] = c.w;
        wn[4*i] = d.x; wn[4*i+1] = d.y; wn[4*i+2] = d.z; wn[4*i+3] = d.w;
      }
    }
    float br = b_hh0[lane], bz = b_hh0[64 + lane], bn = b_hh0[128 + lane];
    float hv = 0.f;
    const float* xwb = xw0 + (size_t)b * TT * 192;
    float xr0 = xwb[      lane], xz0 = xwb[ 64 + lane], xn0 = xwb[128 + lane];
    float xr1 = xwb[192 + lane], xz1 = xwb[256 + lane], xn1 = xwb[320 + lane];
    float xr2 = xwb[384 + lane], xz2 = xwb[448 + lane], xn2 = xwb[512 + lane];
    float xr3 = xwb[576 + lane], xz3 = xwb[640 + lane], xn3 = xwb[704 + lane];

    auto gstep = [&](int s, float xr, float xz, float xn) {
      const float4* hp4 = (const float4*)h0ring[(s + 15) & 15];   // h0(s-1)
      float a0 = br, a1 = 0.f, c0 = bz, c1 = 0.f, d0 = bn, d1 = 0.f;
      #pragma unroll
      for (int i = 0; i < 16; ++i) {
        float4 h4 = hp4[i];
        a0 += wr[4*i+0] * h4.x; a1 += wr[4*i+1] * h4.y;
        a0 += wr[4*i+2] * h4.z; a1 += wr[4*i+3] * h4.w;
        c0 += wz[4*i+0] * h4.x; c1 += wz[4*i+1] * h4.y;
        c0 += wz[4*i+2] * h4.z; c1 += wz[4*i+3] * h4.w;
        d0 += wn[4*i+0] * h4.x; d1 += wn[4*i+1] * h4.y;
        d0 += wn[4*i+2] * h4.z; d1 += wn[4*i+3] * h4.w;
      }
      float r = sigm(xr + (a0 + a1));
      float z = sigm(xz + (c0 + c1));
      float n = tanh_f(xn + r * (d0 + d1));
      hv = (1.f - z) * n + z * hv;
      h0ring[s & 15][lane] = hv;
    };
    auto pf = [&](int s, float& a, float& bb_, float& c) {
      const float* xp = xwb + (size_t)s * 192;
      a = xp[lane]; bb_ = xp[64 + lane]; c = xp[128 + lane];
    };

    for (int s0 = 0; s0 < TT; s0 += 4) {
      if (s0 >= 16) spinwait(w1d, s0 - 13);   // slot reuse vs wave1 (4 groups back)
      bool dopf = (s0 < TT - 4);
      gstep(s0 + 0, xr0, xz0, xn0); if (dopf) pf(s0 + 4, xr0, xz0, xn0);
      gstep(s0 + 1, xr1, xz1, xn1); if (dopf) pf(s0 + 5, xr1, xz1, xn1);
      gstep(s0 + 2, xr2, xz2, xn2); if (dopf) pf(s0 + 6, xr2, xz2, xn2);
      gstep(s0 + 3, xr3, xz3, xn3); if (dopf) pf(s0 + 7, xr3, xz3, xn3);
      asm volatile("" ::: "memory");
      if (lane == 0) *w0d = s0 + 3;
    }
  } else if (wid == 1) {
    // ---- xw1(t) = W_ih1 . h0(t) + b_ih1 ----
    float wr[64], wz[64], wn[64];
    {
      const float4* wrp = (const float4*)(w_ih1 + (size_t)lane * 64);
      const float4* wzp = (const float4*)(w_ih1 + (size_t)(64 + lane) * 64);
      const float4* wnp = (const float4*)(w_ih1 + (size_t)(128 + lane) * 64);
      #pragma unroll
      for (int i = 0; i < 16; ++i) {
        float4 a = wrp[i]; float4 c = wzp[i]; float4 d = wnp[i];
        wr[4*i] = a.x; wr[4*i+1] = a.y; wr[4*i+2] = a.z; wr[4*i+3] = a.w;
        wz[4*i] = c.x; wz[4*i+1] = c.y; wz[4*i+2] = c.z; wz[4*i+3] = c.w;
        wn[4*i] = d.x; wn[4*i+1] = d.y; wn[4*i+2] = d.z; wn[4*i+3] = d.w;
      }
    }
    float br = b_ih1[lane], bz = b_ih1[64 + lane], bn = b_ih1[128 + lane];

    for (int t0 = 0; t0 < TT; t0 += 4) {
      spinwait(w0d, t0 + 3);                   // h0(t0..t0+3) ready
      if (t0 >= 16) spinwait(w2d, t0 - 13);    // slot reuse vs wave2 (4 groups back)
      #pragma unroll
      for (int k = 0; k < 4; ++k) {
        int t = t0 + k;
        const float4* hp4 = (const float4*)h0ring[t & 15];
        float a0 = br, a1 = 0.f, c0 = bz, c1 = 0.f, d0 = bn, d1 = 0.f;
        #pragma unroll
        for (int i = 0; i < 16; ++i) {
          float4 h4 = hp4[i];
          a0 += wr[4*i+0] * h4.x; a1 += wr[4*i+1] * h4.y;
          a0 += wr[4*i+2] * h4.z; a1 += wr[4*i+3] * h4.w;
          c0 += wz[4*i+0] * h4.x; c1 += wz[4*i+1] * h4.y;
          c0 += wz[4*i+2] * h4.z; c1 += wz[4*i+3] * h4.w;
          d0 += wn[4*i+0] * h4.x; d1 += wn[4*i+1] * h4.y;
          d0 += wn[4*i+2] * h4.z; d1 += wn[4*i+3] * h4.w;
        }
        xwring[t & 15][lane]       = a0 + a1;
        xwring[t & 15][64 + lane]  = c0 + c1;
        xwring[t & 15][128 + lane] = d0 + d1;
      }
      asm volatile("" ::: "memory");
      if (lane == 0) *w1d = t0 + 3;
    }
  } else {
    // ---- layer-1 recurrence ----
    float wr[64], wz[64], wn[64];
    {
      const float4* wrp = (const float4*)(w_hh1 + (size_t)lane * 64);
      const float4* wzp = (const float4*)(w_hh1 + (size_t)(64 + lane) * 64);
      const float4* wnp = (const float4*)(w_hh1 + (size_t)(128 + lane) * 64);
      #pragma unroll
      for (int i = 0; i < 16; ++i) {
        float4 a = wrp[i]; float4 c = wzp[i]; float4 d = wnp[i];
        wr[4*i] = a.x; wr[4*i+1] = a.y; wr[4*i+2] = a.z; wr[4*i+3] = a.w;
        wz[4*i] = c.x; wz[4*i+1] = c.y; wz[4*i+2] = c.z; wz[4*i+3] = c.w;
        wn[4*i] = d.x; wn[4*i+1] = d.y; wn[4*i+2] = d.z; wn[4*i+3] = d.w;
      }
    }
    float br = b_hh1[lane], bz = b_hh1[64 + lane], bn = b_hh1[128 + lane];
    float hv = 0.f;
    float* houtb = g1out + (size_t)b * TT * 64 + lane;

    for (int t0 = 0; t0 < TT; t0 += 4) {
      spinwait(w1d, t0 + 3);                   // xw1(t0..t0+3) ready
      #pragma unroll
      for (int k = 0; k < 4; ++k) {
        int t = t0 + k;
        float xr = xwring[t & 15][lane];
        float xz = xwring[t & 15][64 + lane];
        float xn = xwring[t & 15][128 + lane];
        const float4* hp4 = (const float4*)h1pp[t & 1];
        float a0 = br, a1 = 0.f, c0 = bz, c1 = 0.f, d0 = bn, d1 = 0.f;
        #pragma unroll
        for (int i = 0; i < 16; ++i) {
          float4 h4 = hp4[i];
          a0 += wr[4*i+0] * h4.x; a1 += wr[4*i+1] * h4.y;
          a0 += wr[4*i+2] * h4.z; a1 += wr[4*i+3] * h4.w;
          c0 += wz[4*i+0] * h4.x; c1 += wz[4*i+1] * h4.y;
          c0 += wz[4*i+2] * h4.z; c1 += wz[4*i+3] * h4.w;
          d0 += wn[4*i+0] * h4.x; d1 += wn[4*i+1] * h4.y;
          d0 += wn[4*i+2] * h4.z; d1 += wn[4*i+3] * h4.w;
        }
        float r = sigm(xr + (a0 + a1));
        float z = sigm(xz + (c0 + c1));
        float n = tanh_f(xn + r * (d0 + d1));
        hv = (1.f - z) * n + z * hv;
        h1pp[(t + 1) & 1][lane] = hv;
        houtb[(size_t)t * 64] = hv;            // fire-and-forget
      }
      asm volatile("" ::: "memory");
      if (lane == 0) *w2d = t0 + 3;
    }
  }
}

// ---------------- MHA1 qkv projection (K=64, G=192) -> head-major f32 ----------------
extern "C" __global__ void __launch_bounds__(256)
k_qkv(const float* g1, const float* in_w1, const float* in_b1,
      float* q1, float* k1, float* v1) {
  int b  = blockIdx.x >> 4;
  int t0 = (blockIdx.x & 15) << 6;
  int tid = threadIdx.x;
  __shared__ float al[64 * 65];
  const float* act = g1 + ((size_t)b * TT + t0) * 64;
  for (int i = tid; i < 64 * 64; i += 256) {
    int r = i >> 6, c = i & 63;
    al[r * 65 + c] = act[r * 64 + c];
  }
  __syncthreads();
  for (int L = tid; L < 64 * 192; L += 256) {
    int g = L >> 6, r = L & 63;
    const float* wr = in_w1 + (size_t)g * 64;
    const float* ar = &al[r * 65];
    float acc = in_b1[g];
    #pragma unroll
    for (int c = 0; c < 64; ++c) acc += wr[c] * ar[c];
    int p = g / 64;            // 0=q 1=k 2=v
    int rem = g - p * 64;
    int hd = rem >> 5, d = rem & 31;
    float* outp = (p == 0) ? q1 : ((p == 1) ? k1 : v1);
    outp[(((size_t)b * 2 + hd) * TT + t0 + r) * 32 + d] = acc;
  }
}

// ---------------- MHA1 flash attention, key-split S=2: partial (o,m,l) per segment ----------------
extern "C" __global__ void __launch_bounds__(256, 4)
k_attn(const float* q1, const float* k1, const float* v1, float* po, float* ml) {
  int gid = blockIdx.x;
  int b   = gid >> 4;
  int h   = (gid >> 3) & 1;
  int seg = (gid >> 2) & 1;
  int qb  = gid & 3;
  int tid = threadIdx.x;
  int tq  = qb * 256 + tid;
  __shared__ __align__(16) float Kt[64 * 32];
  __shared__ __align__(16) float Vt[64 * 32];
  float q[32], o[32];
  const float* qp = q1 + (((size_t)b * 2 + h) * TT + tq) * 32;
  #pragma unroll
  for (int i = 0; i < 8; ++i) {
    float4 v = ((const float4*)qp)[i];
    q[4 * i] = v.x; q[4 * i + 1] = v.y; q[4 * i + 2] = v.z; q[4 * i + 3] = v.w;
  }
  #pragma unroll
  for (int i = 0; i < 32; ++i) o[i] = 0.f;
  float m = -1e30f, l = 0.f;
  const float scale = 0.17677669529663687f;   // 1/sqrt(32)
  const float4* kb = (const float4*)(k1 + ((size_t)b * 2 + h) * TT * 32);
  const float4* vb = (const float4*)(v1 + ((size_t)b * 2 + h) * TT * 32);
  int k0 = seg << 9;                           // seg*512
  for (int kt = k0; kt < k0 + 512; kt += 64) {
    __syncthreads();
    ((float4*)Kt)[tid]       = kb[kt * 8 + tid];
    ((float4*)Kt)[tid + 256] = kb[kt * 8 + tid + 256];
    ((float4*)Vt)[tid]       = vb[kt * 8 + tid];
    ((float4*)Vt)[tid + 256] = vb[kt * 8 + tid + 256];
    __syncthreads();
    #pragma unroll 1
    for (int c0 = 0; c0 < 64; c0 += 8) {
      float sv[8];
      #pragma unroll
      for (int j = 0; j < 8; ++j) {
        const float4* kr = (const float4*)&Kt[(c0 + j) * 32];
        float a0 = 0, a1 = 0, a2 = 0, a3 = 0;
        #pragma unroll
        for (int i = 0; i < 8; ++i) {
          float4 kv = kr[i];
          a0 += q[4 * i] * kv.x; a1 += q[4 * i + 1] * kv.y;
          a2 += q[4 * i + 2] * kv.z; a3 += q[4 * i + 3] * kv.w;
        }
        sv[j] = ((a0 + a1) + (a2 + a3)) * scale;
      }
      float cm = sv[0];
      #pragma unroll
      for (int j = 1; j < 8; ++j) cm = fmaxf(cm, sv[j]);
      float mnew = fmaxf(m, cm);
      float alpha = __expf(m - mnew);
      float ps = 0.f;
      #pragma unroll
      for (int j = 0; j < 8; ++j) { sv[j] = __expf(sv[j] - mnew); ps += sv[j]; }
      l = l * alpha + ps;
      m = mnew;
      #pragma unroll
      for (int i = 0; i < 8; ++i) {
        float4 acc;
        acc.x = o[4 * i] * alpha; acc.y = o[4 * i + 1] * alpha;
        acc.z = o[4 * i + 2] * alpha; acc.w = o[4 * i + 3] * alpha;
        #pragma unroll
        for (int j = 0; j < 8; ++j) {
          float4 vv = *(const float4*)&Vt[(c0 + j) * 32 + 4 * i];
          acc.x += sv[j] * vv.x; acc.y += sv[j] * vv.y;
          acc.z += sv[j] * vv.z; acc.w += sv[j] * vv.w;
        }
        o[4 * i] = acc.x; o[4 * i + 1] = acc.y; o[4 * i + 2] = acc.z; o[4 * i + 3] = acc.w;
      }
    }
  }
  size_t rbase = (((size_t)(b * 2 + h)) * 2 + seg) * TT + tq;
  float* op = po + rbase * 32;
  #pragma unroll
  for (int i = 0; i < 8; ++i) {
    float4 s4; s4.x = o[4 * i]; s4.y = o[4 * i + 1]; s4.z = o[4 * i + 2]; s4.w = o[4 * i + 3];
    ((float4*)op)[i] = s4;
  }
  ml[rbase * 2 + 0] = m;
  ml[rbase * 2 + 1] = l;
}

// ---------------- combine the two key-segments -> attnO [b][t][64] ----------------
extern "C" __global__ void __launch_bounds__(256)
k_attn_comb(const float* po, const float* ml, float* attnO) {
  int row = blockIdx.x * 256 + threadIdx.x;   // 0 .. 64*2*1024-1
  int bh = row >> 10;
  int t  = row & 1023;
  int b = bh >> 1, h = bh & 1;
  size_t r0 = ((size_t)bh * 2 + 0) * TT + t;
  size_t r1 = ((size_t)bh * 2 + 1) * TT + t;
  float m0 = ml[r0 * 2], l0 = ml[r0 * 2 + 1];
  float m1 = ml[r1 * 2], l1 = ml[r1 * 2 + 1];
  float m = fmaxf(m0, m1);
  float w0 = __expf(m0 - m), w1 = __expf(m1 - m);
  float inv = 1.f / (w0 * l0 + w1 * l1);
  w0 *= inv; w1 *= inv;
  const float4* p0 = (const float4*)(po + r0 * 32);
  const float4* p1 = (const float4*)(po + r1 * 32);
  float* op = attnO + ((size_t)b * TT + t) * 64 + h * 32;
  #pragma unroll
  for (int i = 0; i < 8; ++i) {
    float4 a = p0[i], c = p1[i], r;
    r.x = a.x * w0 + c.x * w1; r.y = a.y * w0 + c.y * w1;
    r.z = a.z * w0 + c.z * w1; r.w = a.w * w0 + c.w * w1;
    ((float4*)op)[i] = r;
  }
}

// ---------------- MHA1 output projection (K=64, G=64) ----------------
extern "C" __global__ void __launch_bounds__(256)
k_oproj(const float* attnO, const float* out_w1, const float* out_b1, float* a1) {
  int b  = blockIdx.x >> 4;
  int t0 = (blockIdx.x & 15) << 6;
  __shared__ float al[64 * 65];
  gemm64(attnO + ((size_t)b * TT + t0) * 64, out_w1, out_b1, al, 64, threadIdx.x,
         a1, 64, ((size_t)b * TT + t0) * 64);
}

// ---------------- MHA2: only the last query row matters -> scores s2 + values v2 ----------------
extern "C" __global__ void __launch_bounds__(256)
k_mha2kv(const float* a1, const float* in_w2, const float* in_b2,
         float* s2, float* v2) {
  int b  = blockIdx.x >> 4;
  int t0 = (blockIdx.x & 15) << 6;
  int tid = threadIdx.x;
  __shared__ float a1r[64 * 65];
  __shared__ float q2s[64];
  __shared__ float alast[64];
  if (tid < 64) alast[tid] = a1[((size_t)b * TT + (TT - 1)) * 64 + tid];
  for (int i = tid; i < 4096; i += 256) {
    int r = i >> 6, e = i & 63;
    a1r[r * 65 + e] = a1[((size_t)b * TT + t0 + r) * 64 + e];
  }
  __syncthreads();
  if (tid < 64) {
    float acc = in_b2[tid];
    const float* wr = in_w2 + (size_t)tid * 64;
    #pragma unroll
    for (int e = 0; e < 64; ++e) acc += alast[e] * wr[e];
    q2s[tid] = acc;
  }
  __syncthreads();
  int tt = tid & 63;
  int role = tid >> 6;
  const float* ar = &a1r[tt * 65];
  const float scale = 0.17677669529663687f;
  if (role < 2) {
    float s = 0.f;
    for (int d = 0; d < 32; ++d) {
      int row = 64 + role * 32 + d;
      const float* wr = in_w2 + (size_t)row * 64;
      float acc = in_b2[row];
      #pragma unroll
      for (int e = 0; e < 64; ++e) acc += ar[e] * wr[e];
      s += q2s[row - 64] * acc;
    }
    s2[((size_t)b * 2 + role) * TT + t0 + tt] = s * scale;
  } else {
    int half = role - 2;
    for (int d = 0; d < 32; ++d) {
      int vd = half * 32 + d;
      int row = 128 + vd;
      const float* wr = in_w2 + (size_t)row * 64;
      float acc = in_b2[row];
      #pragma unroll
      for (int e = 0; e < 64; ++e) acc += ar[e] * wr[e];
      v2[((size_t)b * TT + t0 + tt) * 64 + vd] = acc;
    }
  }
}

// ---------------- MHA2 softmax+PV, out-proj, final MLP ----------------
extern "C" __global__ void __launch_bounds__(256)
k_final(const float* s2, const float* v2,
        const float* out_w2, const float* out_b2,
        const float* w_l, const float* b_l,
        const float* w_l1, const float* b_l1,
        float* out) {
  int b = blockIdx.x;
  int tid = threadIdx.x;
  __shared__ float sm[2 * 1024];
  __shared__ float red[8];
  __shared__ float invl[2];
  __shared__ float opart[4 * 64];
  __shared__ float of[64];
  __shared__ float a2[64];
  __shared__ float hbuf[32];
  __shared__ int bad;
  if (tid == 0) bad = 0;
  for (int i = tid; i < 2048; i += 256) sm[i] = s2[(size_t)b * 2 * TT + i];
  __syncthreads();
  int lane = tid & 63;
  int wid = tid >> 6;
  for (int hh = 0; hh < 2; ++hh) {
    float mx = -1e30f;
    for (int i = tid; i < 1024; i += 256) mx = fmaxf(mx, sm[hh * 1024 + i]);
    #pragma unroll
    for (int off = 32; off > 0; off >>= 1) mx = fmaxf(mx, __shfl_down(mx, off));
    if (lane == 0) red[wid] = mx;
    __syncthreads();
    if (tid == 0) red[4] = fmaxf(fmaxf(red[0], red[1]), fmaxf(red[2], red[3]));
    __syncthreads();
    mx = red[4];
    float s = 0.f;
    for (int i = tid; i < 1024; i += 256) {
      float e = __expf(sm[hh * 1024 + i] - mx);
      sm[hh * 1024 + i] = e;
      s += e;
    }
    #pragma unroll
    for (int off = 32; off > 0; off >>= 1) s += __shfl_down(s, off);
    if (lane == 0) red[wid] = s;
    __syncthreads();
    if (tid == 0) invl[hh] = 1.f / (red[0] + red[1] + red[2] + red[3]);
    __syncthreads();
  }
  {
    int dp = tid & 63;
    int part = tid >> 6;
    int hh = dp >> 5;
    float acc = 0.f;
    for (int t = part * 256; t < part * 256 + 256; ++t)
      acc += sm[hh * 1024 + t] * v2[((size_t)b * TT + t) * 64 + dp];
    opart[part * 64 + dp] = acc;
  }
  __syncthreads();
  if (tid < 64) {
    float o = (opart[tid] + opart[64 + tid] + opart[128 + tid] + opart[192 + tid]) * invl[tid >> 5];
    of[tid] = o;
    if (!finitef(o)) bad = 1;
  }
  __syncthreads();
  if (tid < 64) {
    float acc = out_b2[tid];
    const float* wr = out_w2 + (size_t)tid * 64;
    #pragma unroll
    for (int d = 0; d < 64; ++d) acc += of[d] * wr[d];
    a2[tid] = acc;
  }
  __syncthreads();
  if (tid < 32) {
    float acc = b_l[tid];
    const float* wr = w_l + (size_t)tid * 64;
    #pragma unroll
    for (int e = 0; e < 64; ++e) acc += a2[e] * wr[e];
    hbuf[tid] = fmaxf(acc, 0.f);
  }
  __syncthreads();
  if (tid == 0) {
    float acc = b_l1[0];
    #pragma unroll
    for (int j = 0; j < 32; ++j) acc += hbuf[j] * w_l1[j];
    out[b] = bad ? 777.0f : acc;
  }
}

extern "C" void kernel_launch(void* const* d_in, const int* in_sizes, int n_in,
                              void* d_out, int out_size, void* d_ws, size_t ws_size,
                              hipStream_t stream) {
  const int*   atom_idx  = (const int*)d_in[0];
  const float* bond_dist = (const float*)d_in[1];
  const float* emb       = (const float*)d_in[2];
  const float* w_ih0     = (const float*)d_in[3];
  const float* w_hh0     = (const float*)d_in[4];
  const float* b_ih0     = (const float*)d_in[5];
  const float* b_hh0     = (const float*)d_in[6];
  const float* w_ih1     = (const float*)d_in[7];
  const float* w_hh1     = (const float*)d_in[8];
  const float* b_ih1     = (const float*)d_in[9];
  const float* b_hh1     = (const float*)d_in[10];
  const float* in_w1     = (const float*)d_in[11];
  const float* in_b1     = (const float*)d_in[12];
  const float* out_w1    = (const float*)d_in[13];
  const float* out_b1    = (const float*)d_in[14];
  const float* in_w2     = (const float*)d_in[15];
  const float* in_b2     = (const float*)d_in[16];
  const float* out_w2    = (const float*)d_in[17];
  const float* out_b2    = (const float*)d_in[18];
  const float* w_l       = (const float*)d_in[19];
  const float* b_l       = (const float*)d_in[20];
  const float* w_l1      = (const float*)d_in[21];
  const float* b_l1      = (const float*)d_in[22];

  // Arena plan (84,410,368 B total), all f32:
  //   X @ 0        (50.3 MB): xw0 -> {q,k,v | po} -> v2
  //   A @ 50331648 (16.8 MB): attnO
  //   B @ 67108864 (16.8 MB): g1 -> ml (2MB, during attn) -> a1
  //   D @ 83886080 (0.5 MB):  s2
  char* ws = (char*)d_ws;
  float* X  = (float*)(ws);
  float* A  = (float*)(ws + 50331648);
  float* Bq = (float*)(ws + 67108864);
  float* D  = (float*)(ws + 83886080);
  float* q1 = X;
  float* k1 = X + 4194304;
  float* v1 = X + 8388608;
  float* po = (float*)(ws + 16777216);   // [bh][seg][t][32] = 33,554,432 B, ends exactly at A
  float* ml = Bq;                        // [bh][seg][t][2]  = 2 MB, dead before oproj writes a1

  k_xw0      <<<dim3(1024), dim3(256), 0, stream>>>(atom_idx, bond_dist, emb, w_ih0, b_ih0, X);
  k_grufused <<<dim3(64),   dim3(192), 0, stream>>>(X, w_hh0, b_hh0, w_ih1, b_ih1, w_hh1, b_hh1, Bq);
  k_qkv      <<<dim3(1024), dim3(256), 0, stream>>>(Bq, in_w1, in_b1, q1, k1, v1);
  k_attn     <<<dim3(1024), dim3(256), 0, stream>>>(q1, k1, v1, po, ml);
  k_attn_comb<<<dim3(512),  dim3(256), 0, stream>>>(po, ml, A);
  k_oproj    <<<dim3(1024), dim3(256), 0, stream>>>(A, out_w1, out_b1, Bq);
  k_mha2kv   <<<dim3(1024), dim3(256), 0, stream>>>(Bq, in_w2, in_b2, D, X);
  k_final    <<<dim3(64),   dim3(256), 0, stream>>>(D, X, out_w2, out_b2, w_l, b_l, w_l1, b_l1, (float*)d_out);
}

// Round 8
// 1296.511 us; speedup vs baseline: 1.1974x; 1.1974x over previous
//
#include <hip/hip_runtime.h>

typedef unsigned int uint_t;
typedef float v2f __attribute__((ext_vector_type(2)));

#define BB 64
#define TT 1024

__device__ __forceinline__ float sigm(float x) { return 1.f / (1.f + __expf(-x)); }
__device__ __forceinline__ float tanh_f(float x) { float e = __expf(2.f * x); return 1.f - 2.f / (e + 1.f); }
__device__ __forceinline__ int finitef(float x) { return (x == x) && (fabsf(x) < 1e30f); }

// Bounded wait on an LDS flag (monotone step counter) with s_sleep backoff.
// Cap => sync bug gives wrong answer, not hang.
__device__ __forceinline__ void spinwait(volatile int* f, int v) {
  if (*f >= v) { asm volatile("" ::: "memory"); return; }
  int it = 0;
  while (*f < v && it < (1 << 15)) { __builtin_amdgcn_s_sleep(1); ++it; }
  asm volatile("" ::: "memory");
}

// x feature j of token (b,t): [e_i(0..9) | e_j(10..19) | rbf(20..29)]
__device__ __forceinline__ float feat(int b, int t, int j,
                                      const int* atom_idx, const float* bond_dist,
                                      const float* emb) {
  int ii = atom_idx[(b * TT + t) * 2 + 0];
  if (j < 10) {
    return ii ? emb[ii * 10 + j] : 0.f;
  } else if (j < 20) {
    int jj = atom_idx[(b * TT + t) * 2 + 1];
    return jj ? emb[jj * 10 + (j - 10)] : 0.f;
  } else {
    float d = bond_dist[b * TT + t];
    float c = (float)(j - 19);
    float df = c - d;
    return ii ? __expf(-df * df) : 0.f;
  }
}

// ---------------- xw0 = x @ w_ih0.T + b_ih0  (time-parallel, K=30, G=192) ----------------
extern "C" __global__ void __launch_bounds__(256)
k_xw0(const int* atom_idx, const float* bond_dist, const float* emb,
      const float* w_ih0, const float* b_ih0, float* xw0) {
  int b  = blockIdx.x >> 4;
  int t0 = (blockIdx.x & 15) << 6;
  int tid = threadIdx.x;
  __shared__ float xt[64 * 31];
  for (int i = tid; i < 64 * 30; i += 256) {
    int r = i / 30, j = i % 30;
    xt[r * 31 + j] = feat(b, t0 + r, j, atom_idx, bond_dist, emb);
  }
  __syncthreads();
  for (int L = tid; L < 64 * 192; L += 256) {
    int g = L >> 6, r = L & 63;
    const float* wr = w_ih0 + g * 30;
    const float* ar = &xt[r * 31];
    float acc = b_ih0[g];
    #pragma unroll
    for (int c = 0; c < 30; ++c) acc += wr[c] * ar[c];
    xw0[((size_t)b * TT + t0 + r) * 192 + g] = acc;
  }
}

// ---------------- generic (64 rows) x (G x 64) GEMM ----------------
__device__ __forceinline__ void gemm64(const float* __restrict__ act_g,
                                       const float* __restrict__ w,
                                       const float* __restrict__ bias,
                                       float* al,
                                       int G, int tid,
                                       float* out, int out_rstride, size_t out_base) {
  for (int i = tid; i < 64 * 64; i += 256) {
    int r = i >> 6, c = i & 63;
    al[r * 65 + c] = act_g[r * 64 + c];
  }
  __syncthreads();
  for (int L = tid; L < 64 * G; L += 256) {
    int g = L >> 6, r = L & 63;
    const float* wr = w + (size_t)g * 64;
    const float* ar = &al[r * 65];
    float acc = bias[g];
    #pragma unroll
    for (int c = 0; c < 64; ++c) acc += wr[c] * ar[c];
    out[out_base + (size_t)r * out_rstride + g] = acc;
  }
}

// Load a 64-wide weight row into 32 packed v2f registers.
__device__ __forceinline__ void loadw2(const float* p, v2f* w2) {
  const float4* p4 = (const float4*)p;
  #pragma unroll
  for (int i = 0; i < 16; ++i) {
    float4 a = p4[i];
    v2f lo; lo.x = a.x; lo.y = a.y;
    v2f hi; hi.x = a.z; hi.y = a.w;
    w2[2 * i] = lo; w2[2 * i + 1] = hi;
  }
}

// ---------------- fused GRU0 -> xw1 -> GRU1 : 3-stage wave pipeline, one block/batch ----------------
// wave0: layer-0 recurrence, h0(s) -> LDS ring.   wave1: xw1(t)=W_ih1.h0(t)+b -> LDS ring.
// wave2: layer-1 recurrence -> g1 global.
// Ring depth 16 (4 groups of slack); monotone LDS step counters, s_sleep backoff.
// Matvecs use v2f packed math (v_pk_fma_f32): hipcc does NOT auto-pack scalar FMAs;
// packing halves wave-FMA issue 384->192 cy/step on the serial critical path.
extern "C" __global__ void __launch_bounds__(192, 1)
k_grufused(const float* xw0, const float* w_hh0, const float* b_hh0,
           const float* w_ih1, const float* b_ih1,
           const float* w_hh1, const float* b_hh1, float* g1out) {
  int b    = blockIdx.x;
  int lane = threadIdx.x & 63;
  int wid  = threadIdx.x >> 6;
  __shared__ __align__(16) float h0ring[16][64];
  __shared__ __align__(16) float xwring[16][192];
  __shared__ __align__(16) float h1pp[2][64];
  __shared__ int flags[3];        // w0_done, w1_done, w2_done

  if (threadIdx.x < 3) flags[threadIdx.x] = -1;
  if (wid == 0) h0ring[15][lane] = 0.f;  // h0(-1) = 0
  if (wid == 2) h1pp[0][lane] = 0.f;     // h1(-1) = 0
  __syncthreads();

  volatile int* w0d = &flags[0];
  volatile int* w1d = &flags[1];
  volatile int* w2d = &flags[2];

  if (wid == 0) {
    // ---- layer-0 recurrence ----
    v2f wr2[32], wz2[32], wn2[32];
    loadw2(w_hh0 + (size_t)lane * 64,        wr2);
    loadw2(w_hh0 + (size_t)(64 + lane) * 64, wz2);
    loadw2(w_hh0 + (size_t)(128 + lane) * 64, wn2);
    float br = b_hh0[lane], bz = b_hh0[64 + lane], bn = b_hh0[128 + lane];
    float hv = 0.f;
    const float* xwb = xw0 + (size_t)b * TT * 192;
    float xr0 = xwb[      lane], xz0 = xwb[ 64 + lane], xn0 = xwb[128 + lane];
    float xr1 = xwb[192 + lane], xz1 = xwb[256 + lane], xn1 = xwb[320 + lane];
    float xr2 = xwb[384 + lane], xz2 = xwb[448 + lane], xn2 = xwb[512 + lane];
    float xr3 = xwb[576 + lane], xz3 = xwb[640 + lane], xn3 = xwb[704 + lane];

    auto gstep = [&](int s, float xr, float xz, float xn) {
      const float4* hp4 = (const float4*)h0ring[(s + 15) & 15];   // h0(s-1)
      v2f ar; ar.x = br; ar.y = 0.f;
      v2f az; az.x = bz; az.y = 0.f;
      v2f an; an.x = bn; an.y = 0.f;
      #pragma unroll
      for (int i = 0; i < 16; ++i) {
        float4 h4 = hp4[i];
        v2f hlo; hlo.x = h4.x; hlo.y = h4.y;
        v2f hhi; hhi.x = h4.z; hhi.y = h4.w;
        ar += wr2[2*i] * hlo; ar += wr2[2*i+1] * hhi;
        az += wz2[2*i] * hlo; az += wz2[2*i+1] * hhi;
        an += wn2[2*i] * hlo; an += wn2[2*i+1] * hhi;
      }
      float r = sigm(xr + (ar.x + ar.y));
      float z = sigm(xz + (az.x + az.y));
      float n = tanh_f(xn + r * (an.x + an.y));
      hv = (1.f - z) * n + z * hv;
      h0ring[s & 15][lane] = hv;
    };
    auto pf = [&](int s, float& a, float& bb_, float& c) {
      const float* xp = xwb + (size_t)s * 192;
      a = xp[lane]; bb_ = xp[64 + lane]; c = xp[128 + lane];
    };

    for (int s0 = 0; s0 < TT; s0 += 4) {
      if (s0 >= 16) spinwait(w1d, s0 - 13);   // slot reuse vs wave1 (4 groups back)
      bool dopf = (s0 < TT - 4);
      gstep(s0 + 0, xr0, xz0, xn0); if (dopf) pf(s0 + 4, xr0, xz0, xn0);
      gstep(s0 + 1, xr1, xz1, xn1); if (dopf) pf(s0 + 5, xr1, xz1, xn1);
      gstep(s0 + 2, xr2, xz2, xn2); if (dopf) pf(s0 + 6, xr2, xz2, xn2);
      gstep(s0 + 3, xr3, xz3, xn3); if (dopf) pf(s0 + 7, xr3, xz3, xn3);
      asm volatile("" ::: "memory");
      if (lane == 0) *w0d = s0 + 3;
    }
  } else if (wid == 1) {
    // ---- xw1(t) = W_ih1 . h0(t) + b_ih1 ----
    v2f wr2[32], wz2[32], wn2[32];
    loadw2(w_ih1 + (size_t)lane * 64,        wr2);
    loadw2(w_ih1 + (size_t)(64 + lane) * 64, wz2);
    loadw2(w_ih1 + (size_t)(128 + lane) * 64, wn2);
    float br = b_ih1[lane], bz = b_ih1[64 + lane], bn = b_ih1[128 + lane];

    for (int t0 = 0; t0 < TT; t0 += 4) {
      spinwait(w0d, t0 + 3);                   // h0(t0..t0+3) ready
      if (t0 >= 16) spinwait(w2d, t0 - 13);    // slot reuse vs wave2 (4 groups back)
      #pragma unroll
      for (int k = 0; k < 4; ++k) {
        int t = t0 + k;
        const float4* hp4 = (const float4*)h0ring[t & 15];
        v2f ar; ar.x = br; ar.y = 0.f;
        v2f az; az.x = bz; az.y = 0.f;
        v2f an; an.x = bn; an.y = 0.f;
        #pragma unroll
        for (int i = 0; i < 16; ++i) {
          float4 h4 = hp4[i];
          v2f hlo; hlo.x = h4.x; hlo.y = h4.y;
          v2f hhi; hhi.x = h4.z; hhi.y = h4.w;
          ar += wr2[2*i] * hlo; ar += wr2[2*i+1] * hhi;
          az += wz2[2*i] * hlo; az += wz2[2*i+1] * hhi;
          an += wn2[2*i] * hlo; an += wn2[2*i+1] * hhi;
        }
        xwring[t & 15][lane]       = ar.x + ar.y;
        xwring[t & 15][64 + lane]  = az.x + az.y;
        xwring[t & 15][128 + lane] = an.x + an.y;
      }
      asm volatile("" ::: "memory");
      if (lane == 0) *w1d = t0 + 3;
    }
  } else {
    // ---- layer-1 recurrence ----
    v2f wr2[32], wz2[32], wn2[32];
    loadw2(w_hh1 + (size_t)lane * 64,        wr2);
    loadw2(w_hh1 + (size_t)(64 + lane) * 64, wz2);
    loadw2(w_hh1 + (size_t)(128 + lane) * 64, wn2);
    float br = b_hh1[lane], bz = b_hh1[64 + lane], bn = b_hh1[128 + lane];
    float hv = 0.f;
    float* houtb = g1out + (size_t)b * TT * 64 + lane;

    for (int t0 = 0; t0 < TT; t0 += 4) {
      spinwait(w1d, t0 + 3);                   // xw1(t0..t0+3) ready
      #pragma unroll
      for (int k = 0; k < 4; ++k) {
        int t = t0 + k;
        float xr = xwring[t & 15][lane];
        float xz = xwring[t & 15][64 + lane];
        float xn = xwring[t & 15][128 + lane];
        const float4* hp4 = (const float4*)h1pp[t & 1];
        v2f ar; ar.x = br; ar.y = 0.f;
        v2f az; az.x = bz; az.y = 0.f;
        v2f an; an.x = bn; an.y = 0.f;
        #pragma unroll
        for (int i = 0; i < 16; ++i) {
          float4 h4 = hp4[i];
          v2f hlo; hlo.x = h4.x; hlo.y = h4.y;
          v2f hhi; hhi.x = h4.z; hhi.y = h4.w;
          ar += wr2[2*i] * hlo; ar += wr2[2*i+1] * hhi;
          az += wz2[2*i] * hlo; az += wz2[2*i+1] * hhi;
          an += wn2[2*i] * hlo; an += wn2[2*i+1] * hhi;
        }
        float r = sigm(xr + (ar.x + ar.y));
        float z = sigm(xz + (az.x + az.y));
        float n = tanh_f(xn + r * (an.x + an.y));
        hv = (1.f - z) * n + z * hv;
        h1pp[(t + 1) & 1][lane] = hv;
        houtb[(size_t)t * 64] = hv;            // fire-and-forget
      }
      asm volatile("" ::: "memory");
      if (lane == 0) *w2d = t0 + 3;
    }
  }
}

// ---------------- MHA1 qkv projection (K=64, G=192) -> head-major f32 ----------------
extern "C" __global__ void __launch_bounds__(256)
k_qkv(const float* g1, const float* in_w1, const float* in_b1,
      float* q1, float* k1, float* v1) {
  int b  = blockIdx.x >> 4;
  int t0 = (blockIdx.x & 15) << 6;
  int tid = threadIdx.x;
  __shared__ float al[64 * 65];
  const float* act = g1 + ((size_t)b * TT + t0) * 64;
  for (int i = tid; i < 64 * 64; i += 256) {
    int r = i >> 6, c = i & 63;
    al[r * 65 + c] = act[r * 64 + c];
  }
  __syncthreads();
  for (int L = tid; L < 64 * 192; L += 256) {
    int g = L >> 6, r = L & 63;
    const float* wr = in_w1 + (size_t)g * 64;
    const float* ar = &al[r * 65];
    float acc = in_b1[g];
    #pragma unroll
    for (int c = 0; c < 64; ++c) acc += wr[c] * ar[c];
    int p = g / 64;            // 0=q 1=k 2=v
    int rem = g - p * 64;
    int hd = rem >> 5, d = rem & 31;
    float* outp = (p == 0) ? q1 : ((p == 1) ? k1 : v1);
    outp[(((size_t)b * 2 + hd) * TT + t0 + r) * 32 + d] = acc;
  }
}

// ---------------- MHA1 flash attention, key-split S=2, TWO q-rows per thread ----------------
// R7 analysis: the old kernel was LDS-pipe-bound (1024 broadcast ds_read_b128 per wave
// per K-tile ~= the whole 445us). Processing 2 q-rows/thread makes every Kt/Vt read
// feed 2x the FMAs => DS reads per FLOP halved. Grid 512 blocks (2/CU, 2 waves/SIMD).
extern "C" __global__ void __launch_bounds__(256, 2)
k_attn(const float* q1, const float* k1, const float* v1, float* po, float* ml) {
  int gid = blockIdx.x;          // 512 blocks: b(6)|h(1)|seg(1)|qb(1)
  int b   = gid >> 3;
  int h   = (gid >> 2) & 1;
  int seg = (gid >> 1) & 1;
  int qb  = gid & 1;
  int tid = threadIdx.x;
  int tq0 = qb * 512 + tid;      // rows tq0 and tq0+256
  __shared__ __align__(16) float Kt[64 * 32];
  __shared__ __align__(16) float Vt[64 * 32];
  float qa[32], qc[32], oa[32], oc[32];
  const float* qp0 = q1 + (((size_t)b * 2 + h) * TT + tq0) * 32;
  const float* qp1 = qp0 + 256 * 32;
  #pragma unroll
  for (int i = 0; i < 8; ++i) {
    float4 v0 = ((const float4*)qp0)[i];
    float4 v1r = ((const float4*)qp1)[i];
    qa[4*i] = v0.x; qa[4*i+1] = v0.y; qa[4*i+2] = v0.z; qa[4*i+3] = v0.w;
    qc[4*i] = v1r.x; qc[4*i+1] = v1r.y; qc[4*i+2] = v1r.z; qc[4*i+3] = v1r.w;
  }
  #pragma unroll
  for (int i = 0; i < 32; ++i) { oa[i] = 0.f; oc[i] = 0.f; }
  float m0 = -1e30f, l0 = 0.f, m1 = -1e30f, l1 = 0.f;
  const float scale = 0.17677669529663687f;   // 1/sqrt(32)
  const float4* kb = (const float4*)(k1 + ((size_t)b * 2 + h) * TT * 32);
  const float4* vb = (const float4*)(v1 + ((size_t)b * 2 + h) * TT * 32);
  int k0 = seg << 9;                           // seg*512
  for (int kt = k0; kt < k0 + 512; kt += 64) {
    __syncthreads();
    ((float4*)Kt)[tid]       = kb[kt * 8 + tid];
    ((float4*)Kt)[tid + 256] = kb[kt * 8 + tid + 256];
    ((float4*)Vt)[tid]       = vb[kt * 8 + tid];
    ((float4*)Vt)[tid + 256] = vb[kt * 8 + tid + 256];
    __syncthreads();
    #pragma unroll 1
    for (int c0 = 0; c0 < 64; c0 += 8) {
      float sv0[8], sv1[8];
      #pragma unroll
      for (int j = 0; j < 8; ++j) {
        const float4* kr = (const float4*)&Kt[(c0 + j) * 32];
        float a0 = 0, a1 = 0, c0a = 0, c1a = 0;
        #pragma unroll
        for (int i = 0; i < 8; ++i) {
          float4 kv = kr[i];                       // one broadcast read, 2 q-rows
          a0 += qa[4*i]   * kv.x; a1 += qa[4*i+1] * kv.y;
          a0 += qa[4*i+2] * kv.z; a1 += qa[4*i+3] * kv.w;
          c0a += qc[4*i]   * kv.x; c1a += qc[4*i+1] * kv.y;
          c0a += qc[4*i+2] * kv.z; c1a += qc[4*i+3] * kv.w;
        }
        sv0[j] = (a0 + a1) * scale;
        sv1[j] = (c0a + c1a) * scale;
      }
      float cm0 = sv0[0], cm1 = sv1[0];
      #pragma unroll
      for (int j = 1; j < 8; ++j) { cm0 = fmaxf(cm0, sv0[j]); cm1 = fmaxf(cm1, sv1[j]); }
      float mn0 = fmaxf(m0, cm0), mn1 = fmaxf(m1, cm1);
      float al0 = __expf(m0 - mn0), al1 = __expf(m1 - mn1);
      float ps0 = 0.f, ps1 = 0.f;
      #pragma unroll
      for (int j = 0; j < 8; ++j) {
        sv0[j] = __expf(sv0[j] - mn0); ps0 += sv0[j];
        sv1[j] = __expf(sv1[j] - mn1); ps1 += sv1[j];
      }
      l0 = l0 * al0 + ps0; m0 = mn0;
      l1 = l1 * al1 + ps1; m1 = mn1;
      #pragma unroll
      for (int i = 0; i < 8; ++i) {
        float4 A, C;
        A.x = oa[4*i] * al0; A.y = oa[4*i+1] * al0; A.z = oa[4*i+2] * al0; A.w = oa[4*i+3] * al0;
        C.x = oc[4*i] * al1; C.y = oc[4*i+1] * al1; C.z = oc[4*i+2] * al1; C.w = oc[4*i+3] * al1;
        #pragma unroll
        for (int j = 0; j < 8; ++j) {
          float4 vv = *(const float4*)&Vt[(c0 + j) * 32 + 4 * i];   // shared read
          A.x += sv0[j] * vv.x; A.y += sv0[j] * vv.y; A.z += sv0[j] * vv.z; A.w += sv0[j] * vv.w;
          C.x += sv1[j] * vv.x; C.y += sv1[j] * vv.y; C.z += sv1[j] * vv.z; C.w += sv1[j] * vv.w;
        }
        oa[4*i] = A.x; oa[4*i+1] = A.y; oa[4*i+2] = A.z; oa[4*i+3] = A.w;
        oc[4*i] = C.x; oc[4*i+1] = C.y; oc[4*i+2] = C.z; oc[4*i+3] = C.w;
      }
    }
  }
  size_t rb0 = (((size_t)(b * 2 + h)) * 2 + seg) * TT + tq0;
  size_t rb1 = rb0 + 256;
  float* op0 = po + rb0 * 32;
  float* op1 = po + rb1 * 32;
  #pragma unroll
  for (int i = 0; i < 8; ++i) {
    float4 s0; s0.x = oa[4*i]; s0.y = oa[4*i+1]; s0.z = oa[4*i+2]; s0.w = oa[4*i+3];
    float4 s1; s1.x = oc[4*i]; s1.y = oc[4*i+1]; s1.z = oc[4*i+2]; s1.w = oc[4*i+3];
    ((float4*)op0)[i] = s0;
    ((float4*)op1)[i] = s1;
  }
  ml[rb0 * 2 + 0] = m0; ml[rb0 * 2 + 1] = l0;
  ml[rb1 * 2 + 0] = m1; ml[rb1 * 2 + 1] = l1;
}

// ---------------- combine the two key-segments -> attnO [b][t][64] ----------------
extern "C" __global__ void __launch_bounds__(256)
k_attn_comb(const float* po, const float* ml, float* attnO) {
  int row = blockIdx.x * 256 + threadIdx.x;   // 0 .. 64*2*1024-1
  int bh = row >> 10;
  int t  = row & 1023;
  int b = bh >> 1, h = bh & 1;
  size_t r0 = ((size_t)bh * 2 + 0) * TT + t;
  size_t r1 = ((size_t)bh * 2 + 1) * TT + t;
  float m0 = ml[r0 * 2], l0 = ml[r0 * 2 + 1];
  float m1 = ml[r1 * 2], l1 = ml[r1 * 2 + 1];
  float m = fmaxf(m0, m1);
  float w0 = __expf(m0 - m), w1 = __expf(m1 - m);
  float inv = 1.f / (w0 * l0 + w1 * l1);
  w0 *= inv; w1 *= inv;
  const float4* p0 = (const float4*)(po + r0 * 32);
  const float4* p1 = (const float4*)(po + r1 * 32);
  float* op = attnO + ((size_t)b * TT + t) * 64 + h * 32;
  #pragma unroll
  for (int i = 0; i < 8; ++i) {
    float4 a = p0[i], c = p1[i], r;
    r.x = a.x * w0 + c.x * w1; r.y = a.y * w0 + c.y * w1;
    r.z = a.z * w0 + c.z * w1; r.w = a.w * w0 + c.w * w1;
    ((float4*)op)[i] = r;
  }
}

// ---------------- MHA1 output projection (K=64, G=64) ----------------
extern "C" __global__ void __launch_bounds__(256)
k_oproj(const float* attnO, const float* out_w1, const float* out_b1, float* a1) {
  int b  = blockIdx.x >> 4;
  int t0 = (blockIdx.x & 15) << 6;
  __shared__ float al[64 * 65];
  gemm64(attnO + ((size_t)b * TT + t0) * 64, out_w1, out_b1, al, 64, threadIdx.x,
         a1, 64, ((size_t)b * TT + t0) * 64);
}

// ---------------- MHA2: only the last query row matters -> scores s2 + values v2 ----------------
extern "C" __global__ void __launch_bounds__(256)
k_mha2kv(const float* a1, const float* in_w2, const float* in_b2,
         float* s2, float* v2) {
  int b  = blockIdx.x >> 4;
  int t0 = (blockIdx.x & 15) << 6;
  int tid = threadIdx.x;
  __shared__ float a1r[64 * 65];
  __shared__ float q2s[64];
  __shared__ float alast[64];
  if (tid < 64) alast[tid] = a1[((size_t)b * TT + (TT - 1)) * 64 + tid];
  for (int i = tid; i < 4096; i += 256) {
    int r = i >> 6, e = i & 63;
    a1r[r * 65 + e] = a1[((size_t)b * TT + t0 + r) * 64 + e];
  }
  __syncthreads();
  if (tid < 64) {
    float acc = in_b2[tid];
    const float* wr = in_w2 + (size_t)tid * 64;
    #pragma unroll
    for (int e = 0; e < 64; ++e) acc += alast[e] * wr[e];
    q2s[tid] = acc;
  }
  __syncthreads();
  int tt = tid & 63;
  int role = tid >> 6;
  const float* ar = &a1r[tt * 65];
  const float scale = 0.17677669529663687f;
  if (role < 2) {
    float s = 0.f;
    for (int d = 0; d < 32; ++d) {
      int row = 64 + role * 32 + d;
      const float* wr = in_w2 + (size_t)row * 64;
      float acc = in_b2[row];
      #pragma unroll
      for (int e = 0; e < 64; ++e) acc += ar[e] * wr[e];
      s += q2s[row - 64] * acc;
    }
    s2[((size_t)b * 2 + role) * TT + t0 + tt] = s * scale;
  } else {
    int half = role - 2;
    for (int d = 0; d < 32; ++d) {
      int vd = half * 32 + d;
      int row = 128 + vd;
      const float* wr = in_w2 + (size_t)row * 64;
      float acc = in_b2[row];
      #pragma unroll
      for (int e = 0; e < 64; ++e) acc += ar[e] * wr[e];
      v2[((size_t)b * TT + t0 + tt) * 64 + vd] = acc;
    }
  }
}

// ---------------- MHA2 softmax+PV, out-proj, final MLP ----------------
extern "C" __global__ void __launch_bounds__(256)
k_final(const float* s2, const float* v2,
        const float* out_w2, const float* out_b2,
        const float* w_l, const float* b_l,
        const float* w_l1, const float* b_l1,
        float* out) {
  int b = blockIdx.x;
  int tid = threadIdx.x;
  __shared__ float sm[2 * 1024];
  __shared__ float red[8];
  __shared__ float invl[2];
  __shared__ float opart[4 * 64];
  __shared__ float of[64];
  __shared__ float a2[64];
  __shared__ float hbuf[32];
  __shared__ int bad;
  if (tid == 0) bad = 0;
  for (int i = tid; i < 2048; i += 256) sm[i] = s2[(size_t)b * 2 * TT + i];
  __syncthreads();
  int lane = tid & 63;
  int wid = tid >> 6;
  for (int hh = 0; hh < 2; ++hh) {
    float mx = -1e30f;
    for (int i = tid; i < 1024; i += 256) mx = fmaxf(mx, sm[hh * 1024 + i]);
    #pragma unroll
    for (int off = 32; off > 0; off >>= 1) mx = fmaxf(mx, __shfl_down(mx, off));
    if (lane == 0) red[wid] = mx;
    __syncthreads();
    if (tid == 0) red[4] = fmaxf(fmaxf(red[0], red[1]), fmaxf(red[2], red[3]));
    __syncthreads();
    mx = red[4];
    float s = 0.f;
    for (int i = tid; i < 1024; i += 256) {
      float e = __expf(sm[hh * 1024 + i] - mx);
      sm[hh * 1024 + i] = e;
      s += e;
    }
    #pragma unroll
    for (int off = 32; off > 0; off >>= 1) s += __shfl_down(s, off);
    if (lane == 0) red[wid] = s;
    __syncthreads();
    if (tid == 0) invl[hh] = 1.f / (red[0] + red[1] + red[2] + red[3]);
    __syncthreads();
  }
  {
    int dp = tid & 63;
    int part = tid >> 6;
    int hh = dp >> 5;
    float acc = 0.f;
    for (int t = part * 256; t < part * 256 + 256; ++t)
      acc += sm[hh * 1024 + t] * v2[((size_t)b * TT + t) * 64 + dp];
    opart[part * 64 + dp] = acc;
  }
  __syncthreads();
  if (tid < 64) {
    float o = (opart[tid] + opart[64 + tid] + opart[128 + tid] + opart[192 + tid]) * invl[tid >> 5];
    of[tid] = o;
    if (!finitef(o)) bad = 1;
  }
  __syncthreads();
  if (tid < 64) {
    float acc = out_b2[tid];
    const float* wr = out_w2 + (size_t)tid * 64;
    #pragma unroll
    for (int d = 0; d < 64; ++d) acc += of[d] * wr[d];
    a2[tid] = acc;
  }
  __syncthreads();
  if (tid < 32) {
    float acc = b_l[tid];
    const float* wr = w_l + (size_t)tid * 64;
    #pragma unroll
    for (int e = 0; e < 64; ++e) acc += a2[e] * wr[e];
    hbuf[tid] = fmaxf(acc, 0.f);
  }
  __syncthreads();
  if (tid == 0) {
    float acc = b_l1[0];
    #pragma unroll
    for (int j = 0; j < 32; ++j) acc += hbuf[j] * w_l1[j];
    out[b] = bad ? 777.0f : acc;
  }
}

extern "C" void kernel_launch(void* const* d_in, const int* in_sizes, int n_in,
                              void* d_out, int out_size, void* d_ws, size_t ws_size,
                              hipStream_t stream) {
  const int*   atom_idx  = (const int*)d_in[0];
  const float* bond_dist = (const float*)d_in[1];
  const float* emb       = (const float*)d_in[2];
  const float* w_ih0     = (const float*)d_in[3];
  const float* w_hh0     = (const float*)d_in[4];
  const float* b_ih0     = (const float*)d_in[5];
  const float* b_hh0     = (const float*)d_in[6];
  const float* w_ih1     = (const float*)d_in[7];
  const float* w_hh1     = (const float*)d_in[8];
  const float* b_ih1     = (const float*)d_in[9];
  const float* b_hh1     = (const float*)d_in[10];
  const float* in_w1     = (const float*)d_in[11];
  const float* in_b1     = (const float*)d_in[12];
  const float* out_w1    = (const float*)d_in[13];
  const float* out_b1    = (const float*)d_in[14];
  const float* in_w2     = (const float*)d_in[15];
  const float* in_b2     = (const float*)d_in[16];
  const float* out_w2    = (const float*)d_in[17];
  const float* out_b2    = (const float*)d_in[18];
  const float* w_l       = (const float*)d_in[19];
  const float* b_l       = (const float*)d_in[20];
  const float* w_l1      = (const float*)d_in[21];
  const float* b_l1      = (const float*)d_in[22];

  // Arena plan (84,410,368 B total), all f32:
  //   X @ 0        (50.3 MB): xw0 -> {q,k,v | po} -> v2
  //   A @ 50331648 (16.8 MB): attnO
  //   B @ 67108864 (16.8 MB): g1 -> ml (2MB, during attn) -> a1
  //   D @ 83886080 (0.5 MB):  s2
  char* ws = (char*)d_ws;
  float* X  = (float*)(ws);
  float* A  = (float*)(ws + 50331648);
  float* Bq = (float*)(ws + 67108864);
  float* D  = (float*)(ws + 83886080);
  float* q1 = X;
  float* k1 = X + 4194304;
  float* v1 = X + 8388608;
  float* po = (float*)(ws + 16777216);   // [bh][seg][t][32] = 33,554,432 B, ends exactly at A
  float* ml = Bq;                        // [bh][seg][t][2]  = 2 MB, dead before oproj writes a1

  k_xw0      <<<dim3(1024), dim3(256), 0, stream>>>(atom_idx, bond_dist, emb, w_ih0, b_ih0, X);
  k_grufused <<<dim3(64),   dim3(192), 0, stream>>>(X, w_hh0, b_hh0, w_ih1, b_ih1, w_hh1, b_hh1, Bq);
  k_qkv      <<<dim3(1024), dim3(256), 0, stream>>>(Bq, in_w1, in_b1, q1, k1, v1);
  k_attn     <<<dim3(512),  dim3(256), 0, stream>>>(q1, k1, v1, po, ml);
  k_attn_comb<<<dim3(512),  dim3(256), 0, stream>>>(po, ml, A);
  k_oproj    <<<dim3(1024), dim3(256), 0, stream>>>(A, out_w1, out_b1, Bq);
  k_mha2kv   <<<dim3(1024), dim3(256), 0, stream>>>(Bq, in_w2, in_b2, D, X);
  k_final    <<<dim3(64),   dim3(256), 0, stream>>>(D, X, out_w2, out_b2, w_l, b_l, w_l1, b_l1, (float*)d_out);
}